// Round 12
// baseline (83.381 us; speedup 1.0000x reference)
//
#include <hip/hip_runtime.h>

// Problem constants: N=512, L=16, HOP=8, M=8, C=2, K=6000
#define NN   512
#define LL   16
#define MM   8
#define CC   2
#define KK   6000
#define TT   ((KK - 1) * 8 + 16)      // 48008
#define KW   256                      // k-columns per block -> 1KB granule/row
#define NKB  24                       // ceil(6000/256)
#define CHR  8                        // rows per chunk (1 per wave)
#define NC   (NN / CHR)               // 64 chunks
#define ROWB (KK * 4)                 // 24000 bytes per n-row
#define TENS_B (CHR * 1024)           // 8192 B per tensor per buffer
#define BUF_B  (3 * TENS_B)           // 24576 B per buffer

typedef __attribute__((address_space(3))) void       lds_v;
typedef __attribute__((address_space(1))) const void glob_v;

// 1KB-granule experiment. 512 threads = 8 waves = 4 n-groups x 2 k-half
// waves. Each DMA instr = 64 lanes x 16B = ONE row x 1KB CONTIGUOUS
// (granule 512B -> 1KB vs R6). Wave wq stages local row wq (3 tensors);
// group g = wq>>1 consumes rows {2g, 2g+1}; thread p = (wq&1)*64+t owns
// k = kb*256 + {2p, 2p+1}. Cross-wave dep handled HK-style: counted
// s_waitcnt vmcnt(3) + raw s_barrier (c+1 loads stay in flight across it),
// second barrier after compute guards buffer reuse. XCD banding: 3
// consecutive kb per XCD per m. 4-group LDS tree-reduce -> group 0;
// 2-k OLA per wave with 2-term commutative seam atomics (t==0 lo seam,
// t==63 hi seam — covers both block seams and the intra-pair seam).
__global__ __launch_bounds__(512, 4) void decoder_dma_kernel(
    const float* __restrict__ inputs,    // [M, N, K]
    const float* __restrict__ est_mask,  // [M, C, N, K]
    const float* __restrict__ W,         // [N, L]
    float* __restrict__ out)             // [M, C, T], pre-zeroed
{
    __shared__ __align__(16) char lds[2 * BUF_B];   // 48 KB

    // ---- swizzled block -> (kb, m): XCD x owns kb in [x*3, x*3+3) ----
    const int bid = blockIdx.x;          // 0..191
    const int xcd = bid & 7;
    const int s   = bid >> 3;            // 0..23
    const int kb  = xcd * 3 + (s % 3);   // 0..23
    const int m   = s / 3;               // 0..7

    const int tid = threadIdx.x;
    const int t   = tid & 63;                                  // lane
    const int wq  = __builtin_amdgcn_readfirstlane(tid >> 6);  // wave 0..7
    const int g   = wq >> 1;             // n-group 0..3
    const int p   = (wq & 1) * 64 + t;   // k-pair index 0..127

    // per-lane DMA source: 16B slice t of the block's 1KB row segment.
    // Clamp for the kb=23 tail (results discarded by the kA<KK guard).
    int cb = kb * 1024 + t * 16;
    if (cb > ROWB - 16) cb = ROWB - 16;

    const char* tb0 = (const char*)inputs   + (size_t)m * NN * ROWB;
    const char* tb1 = (const char*)est_mask + (size_t)(m * CC) * NN * ROWB;
    const char* tb2 = tb1 + (size_t)NN * ROWB;

    // wave wq stages global row c*8+wq for all 3 tensors (1KB each)
    auto issue = [&](int c, int bsel) {
        const size_t off = (size_t)(c * CHR + wq) * ROWB + cb;
        char* bb = lds + bsel * BUF_B + wq * 1024;
        __builtin_amdgcn_global_load_lds((glob_v*)(tb0 + off), (lds_v*)(bb),              16, 0, 0);
        __builtin_amdgcn_global_load_lds((glob_v*)(tb1 + off), (lds_v*)(bb + TENS_B),     16, 0, 0);
        __builtin_amdgcn_global_load_lds((glob_v*)(tb2 + off), (lds_v*)(bb + 2 * TENS_B), 16, 0, 0);
    };

    float a0A[LL], a0B[LL], a1A[LL], a1B[LL];        // acc[c][kA/kB][l]
    #pragma unroll
    for (int l = 0; l < LL; ++l) { a0A[l] = 0.f; a0B[l] = 0.f; a1A[l] = 0.f; a1B[l] = 0.f; }

    issue(0, 0);
    issue(1, 1);

    for (int c = 0; c < NC; ++c) {
        if (c + 1 < NC) {
            // outstanding: [c:3][c+1:3] -> wait own c loads; c+1 in flight
            asm volatile("s_waitcnt vmcnt(3)" ::: "memory");
        } else {
            asm volatile("s_waitcnt vmcnt(0)" ::: "memory");
        }
        __builtin_amdgcn_sched_barrier(0);
        __builtin_amdgcn_s_barrier();        // partner's c loads also landed
        __builtin_amdgcn_sched_barrier(0);

        const char* Lb = lds + (c & 1) * BUF_B;

        #pragma unroll
        for (int rloc = 0; rloc < 2; ++rloc) {
            const int lr = 2 * g + rloc;             // local row (staged by wave lr)
            const int n  = c * CHR + lr;             // wave-uniform -> s_load W
            float wv[LL];
            *reinterpret_cast<float4*>(&wv[0])  = *(const float4*)(W + n * LL + 0);
            *reinterpret_cast<float4*>(&wv[4])  = *(const float4*)(W + n * LL + 4);
            *reinterpret_cast<float4*>(&wv[8])  = *(const float4*)(W + n * LL + 8);
            *reinterpret_cast<float4*>(&wv[12]) = *(const float4*)(W + n * LL + 12);

            const float2 vin = *reinterpret_cast<const float2*>(Lb + lr * 1024 + p * 8);
            const float2 vm0 = *reinterpret_cast<const float2*>(Lb + TENS_B + lr * 1024 + p * 8);
            const float2 vm1 = *reinterpret_cast<const float2*>(Lb + 2 * TENS_B + lr * 1024 + p * 8);
            const float x0A = vin.x * vm0.x, x0B = vin.y * vm0.y;
            const float x1A = vin.x * vm1.x, x1B = vin.y * vm1.y;
            #pragma unroll
            for (int l = 0; l < LL; ++l) {
                a0A[l] = fmaf(x0A, wv[l], a0A[l]);
                a0B[l] = fmaf(x0B, wv[l], a0B[l]);
                a1A[l] = fmaf(x1A, wv[l], a1A[l]);
                a1B[l] = fmaf(x1B, wv[l], a1B[l]);
            }
        }

        __builtin_amdgcn_sched_barrier(0);
        __builtin_amdgcn_s_barrier();        // all waves done reading buf[c&1]
        __builtin_amdgcn_sched_barrier(0);
        if (c + 2 < NC) issue(c + 2, c & 1); // safe: buffer free, loads overlap
    }

    // ---- all waves done; safe to reuse LDS ----
    __syncthreads();

    // ---- tree-reduce 4 n-groups -> group 0 (stride 33/67 -> 2-way free) ----
    float* sm = (float*)lds;
    // round 1, c=0: groups 2,3 -> 0,1 (32 floats/thread, stride 33)
    if (g >= 2) {
        float* d = &sm[((g - 2) * 128 + p) * 33];
        #pragma unroll
        for (int l = 0; l < LL; ++l) { d[l] = a0A[l]; d[16 + l] = a0B[l]; }
    }
    __syncthreads();
    if (g < 2) {
        const float* sp = &sm[(g * 128 + p) * 33];
        #pragma unroll
        for (int l = 0; l < LL; ++l) { a0A[l] += sp[l]; a0B[l] += sp[16 + l]; }
    }
    __syncthreads();
    // round 1, c=1
    if (g >= 2) {
        float* d = &sm[((g - 2) * 128 + p) * 33];
        #pragma unroll
        for (int l = 0; l < LL; ++l) { d[l] = a1A[l]; d[16 + l] = a1B[l]; }
    }
    __syncthreads();
    if (g < 2) {
        const float* sp = &sm[(g * 128 + p) * 33];
        #pragma unroll
        for (int l = 0; l < LL; ++l) { a1A[l] += sp[l]; a1B[l] += sp[16 + l]; }
    }
    __syncthreads();
    // round 2: group 1 -> group 0 (64 floats/thread, stride 67)
    if (g == 1) {
        float* d = &sm[p * 67];
        #pragma unroll
        for (int l = 0; l < LL; ++l) {
            d[l] = a0A[l]; d[16 + l] = a0B[l];
            d[32 + l] = a1A[l]; d[48 + l] = a1B[l];
        }
    }
    __syncthreads();

    if (g == 0) {
        {
            const float* sp = &sm[p * 67];
            #pragma unroll
            for (int l = 0; l < LL; ++l) {
                a0A[l] += sp[l]; a0B[l] += sp[16 + l];
                a1A[l] += sp[32 + l]; a1B[l] += sp[48 + l];
            }
        }

        // ---- overlap-and-add (2-k scheme, per wave of the pair) ----
        const int kA = kb * KW + 2 * p;
        // prev-hi for kA comes from lane t-1's kB hi half (within wave)
        float ph0[8], ph1[8];
        #pragma unroll
        for (int j = 0; j < 8; ++j) {
            ph0[j] = __shfl_up(a0B[8 + j], 1);
            ph1[j] = __shfl_up(a1B[8 + j], 1);
        }

        if (kA < KK) {
            float* o0 = out + ((size_t)m * CC + 0) * TT + 8 * kA;
            float* o1 = out + ((size_t)m * CC + 1) * TT + 8 * kA;

            if (t == 0) {
                // lo seam: block boundary (wave 0) or intra-pair (wave 1);
                // pairs with the preceding lane's hi atomic
                #pragma unroll
                for (int j = 0; j < 8; ++j) {
                    atomicAdd(&o0[j], a0A[j]);
                    atomicAdd(&o1[j], a1A[j]);
                }
            } else {
                #pragma unroll
                for (int j = 0; j < 8; ++j) {
                    o0[j] = a0A[j] + ph0[j];
                    o1[j] = a1A[j] + ph1[j];
                }
            }
            // kB lo + kA hi: both terms in-lane
            #pragma unroll
            for (int j = 0; j < 8; ++j) {
                o0[8 + j] = a0B[j] + a0A[8 + j];
                o1[8 + j] = a1B[j] + a1A[8 + j];
            }
            // kB hi: consumed by the next lane's lo unless seam / tail
            const int kB = kA + 1;
            if (t == 63 || kB == KK - 1) {
                #pragma unroll
                for (int j = 0; j < 8; ++j) {
                    atomicAdd(&o0[16 + j], a0B[8 + j]);
                    atomicAdd(&o1[16 + j], a1B[8 + j]);
                }
            }
        }
    }
}

extern "C" void kernel_launch(void* const* d_in, const int* in_sizes, int n_in,
                              void* d_out, int out_size, void* d_ws, size_t ws_size,
                              hipStream_t stream) {
    const float* inputs   = (const float*)d_in[0];  // [8, 512, 6000]
    const float* est_mask = (const float*)d_in[1];  // [8, 2, 512, 6000]
    const float* W        = (const float*)d_in[2];  // [512, 16]
    float*       out      = (float*)d_out;          // [8, 2, 48008]

    hipMemsetAsync(out, 0, (size_t)out_size * sizeof(float), stream);

    decoder_dma_kernel<<<dim3(NKB * MM), 512, 0, stream>>>(inputs, est_mask, W, out);
}

// Round 13
// 59.825 us; speedup vs baseline: 1.3938x; 1.3938x over previous
//
#include <hip/hip_runtime.h>

// Problem constants: N=512, L=16, HOP=8, M=8, C=2, K=6000
#define NN   512
#define LL   16
#define MM   8
#define CC   2
#define KK   6000
#define TT   ((KK - 1) * 8 + 16)      // 48008
#define KW   128                      // k-columns per block -> 512B granule/row
#define NKB  47                       // ceil(6000/128) real k-blocks
#define NKBP 48                       // padded to 8*6 for XCD banding
#define NCH  16                       // n-rows per chunk (8 waves x 2 rows)
#define NC   (NN / NCH)               // 32 chunks
#define ROWB (KK * 4)                 // 24000 bytes per n-row
#define TENS_B (NCH * KW * 4)         // 8192 B per tensor per buffer
#define BUF_B  (3 * TENS_B)           // 24576 B per buffer

typedef __attribute__((address_space(3))) void       lds_v;
typedef __attribute__((address_space(1))) const void glob_v;

// BEST MEASURED (R6/R11: 58.88 / 58.94 us, ~98% of the measured ~5.1 TB/s
// combined read-path ceiling for this pattern; granule (R12) / balance (R9)
// / dispatch (R10) / pipeline (R5) levers all exhausted at <= this time).
// 512 threads = 8 waves. Lane t handles k = kb*128 + {2t, 2t+1}.
// Wave-self-sufficient DMA: wave wq issues exactly 3 global_load_lds per
// chunk (its own 2 rows x 512B x 3 tensors; each instr = 64 lanes x 16B =
// 2 rows x 512B CONTIGUOUS) -> counted s_waitcnt vmcnt(3), no barriers in
// the main loop. XCD banding: bid&7 -> band of 6 consecutive kb per XCD
// (L2 locality; FETCH 180->148 MB). Tree-reduce 8 waves -> wave 0,
// in-register overlap-add (2-k scheme), 2-term commutative seam atomics
// on zeroed out (deterministic).
__global__ __launch_bounds__(512, 4) void decoder_dma_kernel(
    const float* __restrict__ inputs,    // [M, N, K]
    const float* __restrict__ est_mask,  // [M, C, N, K]
    const float* __restrict__ W,         // [N, L]
    float* __restrict__ out)             // [M, C, T], pre-zeroed
{
    __shared__ __align__(16) char lds[2 * BUF_B];   // 48 KB

    // ---- swizzled block -> (kb, m): XCD x owns kb in [x*6, x*6+6) ----
    const int bid = blockIdx.x;          // 0..383
    const int xcd = bid & 7;
    const int s   = bid >> 3;            // 0..47
    const int kb  = xcd * 6 + (s % 6);   // 0..47
    const int m   = s / 6;               // 0..7
    if (kb >= NKB) return;               // 8 padded dummy blocks

    const int tid = threadIdx.x;
    const int t   = tid & 63;                        // lane
    const int wq  = __builtin_amdgcn_readfirstlane(tid >> 6);  // wave 0..7

    // per-lane DMA source: lane covers row (t>>5) of the wave's 2-row pair,
    // 16B slice (t&31) of the row's 512B segment. Clamp for the kb=46 tail
    // (those lanes' results are discarded by the kA<KK guard).
    const int lane_r = t >> 5;
    int cb = kb * 512 + (t & 31) * 16;
    if (cb > ROWB - 16) cb = ROWB - 16;
    const size_t lane_off = (size_t)lane_r * ROWB + cb;

    const char* tb0 = (const char*)inputs   + (size_t)m * NN * ROWB;
    const char* tb1 = (const char*)est_mask + (size_t)(m * CC) * NN * ROWB;
    const char* tb2 = tb1 + (size_t)NN * ROWB;

    char* dst_base = lds + wq * 1024;    // wave's 2-row (1KB) slot per tensor

    auto issue = [&](int c, int bsel) {
        const size_t rowoff = (size_t)(c * NCH + wq * 2) * ROWB + lane_off;
        char* bb = dst_base + bsel * BUF_B;
        __builtin_amdgcn_global_load_lds((glob_v*)(tb0 + rowoff), (lds_v*)(bb),              16, 0, 0);
        __builtin_amdgcn_global_load_lds((glob_v*)(tb1 + rowoff), (lds_v*)(bb + TENS_B),     16, 0, 0);
        __builtin_amdgcn_global_load_lds((glob_v*)(tb2 + rowoff), (lds_v*)(bb + 2 * TENS_B), 16, 0, 0);
    };

    float a0A[LL], a0B[LL], a1A[LL], a1B[LL];        // acc[c][kA/kB][l]
    #pragma unroll
    for (int l = 0; l < LL; ++l) { a0A[l] = 0.f; a0B[l] = 0.f; a1A[l] = 0.f; a1B[l] = 0.f; }

    issue(0, 0);

    for (int c = 0; c < NC; ++c) {
        if (c + 1 < NC) {
            issue(c + 1, (c + 1) & 1);
            // outstanding: [c:3][c+1:3] -> wait <=3 left: c landed, c+1 in flight
            asm volatile("s_waitcnt vmcnt(3)" ::: "memory");
        } else {
            asm volatile("s_waitcnt vmcnt(0)" ::: "memory");
        }
        __builtin_amdgcn_sched_barrier(0);   // no hoisting past the waitcnt

        const char* Lb = lds + (c & 1) * BUF_B + wq * 1024;

        #pragma unroll
        for (int r = 0; r < 2; ++r) {
            const int n = c * NCH + wq * 2 + r;      // wave-uniform -> s_load W
            float wv[LL];
            *reinterpret_cast<float4*>(&wv[0])  = *(const float4*)(W + n * LL + 0);
            *reinterpret_cast<float4*>(&wv[4])  = *(const float4*)(W + n * LL + 4);
            *reinterpret_cast<float4*>(&wv[8])  = *(const float4*)(W + n * LL + 8);
            *reinterpret_cast<float4*>(&wv[12]) = *(const float4*)(W + n * LL + 12);

            const float2 vin = reinterpret_cast<const float2*>(Lb + r * 512)[t];
            const float2 vm0 = reinterpret_cast<const float2*>(Lb + TENS_B + r * 512)[t];
            const float2 vm1 = reinterpret_cast<const float2*>(Lb + 2 * TENS_B + r * 512)[t];
            const float x0A = vin.x * vm0.x, x0B = vin.y * vm0.y;
            const float x1A = vin.x * vm1.x, x1B = vin.y * vm1.y;
            #pragma unroll
            for (int l = 0; l < LL; ++l) {
                a0A[l] = fmaf(x0A, wv[l], a0A[l]);
                a0B[l] = fmaf(x0B, wv[l], a0B[l]);
                a1A[l] = fmaf(x1A, wv[l], a1A[l]);
                a1B[l] = fmaf(x1B, wv[l], a1B[l]);
            }
        }
    }

    // ---- all waves done (own DMA drained); safe to reuse LDS ----
    __syncthreads();

    // ---- tree-reduce 8 waves -> wave 0 (verified R3/R6 scheme) ----
    float* sm = (float*)lds;
    // act=4, phase c=0 (32 floats/thread, stride 33 -> 2-way free)
    if (wq >= 4) {
        float* d = &sm[((wq - 4) * 64 + t) * 33];
        #pragma unroll
        for (int l = 0; l < LL; ++l) { d[l] = a0A[l]; d[16 + l] = a0B[l]; }
    }
    __syncthreads();
    if (wq < 4) {
        const float* sp = &sm[(wq * 64 + t) * 33];
        #pragma unroll
        for (int l = 0; l < LL; ++l) { a0A[l] += sp[l]; a0B[l] += sp[16 + l]; }
    }
    __syncthreads();
    // act=4, phase c=1
    if (wq >= 4) {
        float* d = &sm[((wq - 4) * 64 + t) * 33];
        #pragma unroll
        for (int l = 0; l < LL; ++l) { d[l] = a1A[l]; d[16 + l] = a1B[l]; }
    }
    __syncthreads();
    if (wq < 4) {
        const float* sp = &sm[(wq * 64 + t) * 33];
        #pragma unroll
        for (int l = 0; l < LL; ++l) { a1A[l] += sp[l]; a1B[l] += sp[16 + l]; }
    }
    __syncthreads();
    // act=2, both c (64 floats/thread, stride 67 -> 2-way free)
    if (wq == 2 || wq == 3) {
        float* d = &sm[((wq - 2) * 64 + t) * 67];
        #pragma unroll
        for (int l = 0; l < LL; ++l) {
            d[l] = a0A[l]; d[16 + l] = a0B[l];
            d[32 + l] = a1A[l]; d[48 + l] = a1B[l];
        }
    }
    __syncthreads();
    if (wq < 2) {
        const float* sp = &sm[(wq * 64 + t) * 67];
        #pragma unroll
        for (int l = 0; l < LL; ++l) {
            a0A[l] += sp[l]; a0B[l] += sp[16 + l];
            a1A[l] += sp[32 + l]; a1B[l] += sp[48 + l];
        }
    }
    __syncthreads();
    // act=1
    if (wq == 1) {
        float* d = &sm[t * 67];
        #pragma unroll
        for (int l = 0; l < LL; ++l) {
            d[l] = a0A[l]; d[16 + l] = a0B[l];
            d[32 + l] = a1A[l]; d[48 + l] = a1B[l];
        }
    }
    __syncthreads();

    if (wq == 0) {
        {
            const float* sp = &sm[t * 67];
            #pragma unroll
            for (int l = 0; l < LL; ++l) {
                a0A[l] += sp[l]; a0B[l] += sp[16 + l];
                a1A[l] += sp[32 + l]; a1B[l] += sp[48 + l];
            }
        }

        // ---- overlap-and-add (2-k scheme) ----
        const int kA = kb * KW + 2 * t;
        // prev-hi for kA comes from lane t-1's kB hi half
        float ph0[8], ph1[8];
        #pragma unroll
        for (int j = 0; j < 8; ++j) {
            ph0[j] = __shfl_up(a0B[8 + j], 1);
            ph1[j] = __shfl_up(a1B[8 + j], 1);
        }

        if (kA < KK) {
            float* o0 = out + ((size_t)m * CC + 0) * TT + 8 * kA;
            float* o1 = out + ((size_t)m * CC + 1) * TT + 8 * kA;

            if (t == 0) {
                // lo of first frame in block: pairs with prev block's hi atomic
                #pragma unroll
                for (int j = 0; j < 8; ++j) {
                    atomicAdd(&o0[j], a0A[j]);
                    atomicAdd(&o1[j], a1A[j]);
                }
            } else {
                #pragma unroll
                for (int j = 0; j < 8; ++j) {
                    o0[j] = a0A[j] + ph0[j];
                    o1[j] = a1A[j] + ph1[j];
                }
            }
            // kB lo + kA hi: both terms in-lane
            #pragma unroll
            for (int j = 0; j < 8; ++j) {
                o0[8 + j] = a0B[j] + a0A[8 + j];
                o1[8 + j] = a1B[j] + a1A[8 + j];
            }
            // kB hi: consumed by lane t+1 unless block seam / global tail
            const int kB = kA + 1;
            if (t == 63 || kB == KK - 1) {
                #pragma unroll
                for (int j = 0; j < 8; ++j) {
                    atomicAdd(&o0[16 + j], a0B[8 + j]);
                    atomicAdd(&o1[16 + j], a1B[8 + j]);
                }
            }
        }
    }
}

extern "C" void kernel_launch(void* const* d_in, const int* in_sizes, int n_in,
                              void* d_out, int out_size, void* d_ws, size_t ws_size,
                              hipStream_t stream) {
    const float* inputs   = (const float*)d_in[0];  // [8, 512, 6000]
    const float* est_mask = (const float*)d_in[1];  // [8, 2, 512, 6000]
    const float* W        = (const float*)d_in[2];  // [512, 16]
    float*       out      = (float*)d_out;          // [8, 2, 48008]

    hipMemsetAsync(out, 0, (size_t)out_size * sizeof(float), stream);

    decoder_dma_kernel<<<dim3(NKBP * MM), 512, 0, stream>>>(inputs, est_mask, W, out);
}